// Round 1
// baseline (776.391 us; speedup 1.0000x reference)
//
#include <hip/hip_runtime.h>
#include <math.h>

#define B_ 8
#define H_ 56
#define W_ 56
#define C_ 64
#define N_ (H_*W_)      // 3136
#define QT 64
#define KT 64

// ---------------------------------------------------------------------------
// Kernel 1: fused depthwise 3x3 conv -> q, k, v  (all three read x once)
// ---------------------------------------------------------------------------
__global__ __launch_bounds__(256)
void dwconv_qkv(const float* __restrict__ x,
                const float* __restrict__ wq, const float* __restrict__ bq,
                const float* __restrict__ wk, const float* __restrict__ bk,
                const float* __restrict__ wv, const float* __restrict__ bv,
                float* __restrict__ q, float* __restrict__ k, float* __restrict__ v) {
    int idx = blockIdx.x * 256 + threadIdx.x;
    if (idx >= B_ * N_ * C_) return;
    int c   = idx & 63;
    int pix = idx >> 6;
    int w0  = pix % W_;
    int h0  = (pix / W_) % H_;
    int b   = pix / (W_ * H_);

    float aq = bq[c], ak = bk[c], av = bv[c];
    #pragma unroll
    for (int dh = 0; dh < 3; ++dh) {
        int h = h0 + dh - 1;
        if (h < 0 || h >= H_) continue;
        #pragma unroll
        for (int dw = 0; dw < 3; ++dw) {
            int w = w0 + dw - 1;
            if (w < 0 || w >= W_) continue;
            float xv = x[(((size_t)b * H_ + h) * W_ + w) * C_ + c];
            int wi = (dh * 3 + dw) * C_ + c;
            aq = fmaf(xv, wq[wi], aq);
            ak = fmaf(xv, wk[wi], ak);
            av = fmaf(xv, wv[wi], av);
        }
    }
    q[idx] = aq; k[idx] = ak; v[idx] = av;
}

// ---------------------------------------------------------------------------
// Kernel 2: flash attention (fp32 vector FMA) + fused output projection
//   grid = (N/QT, B), block = 256
//   LDS: Qs/Ks/Vs [64][64] f32, XOR-swizzled at float4 granularity:
//        element (row, 4*cc+e) stored at row*64 + 4*(cc ^ (row&15)) + e
//   Ss [64][65] (scalar access only; 65-stride -> 2-way max)
// ---------------------------------------------------------------------------
__global__ __launch_bounds__(256, 2)
void flash_attn(const float* __restrict__ q, const float* __restrict__ k,
                const float* __restrict__ v, const float* __restrict__ Wp,
                const float* __restrict__ bp, float* __restrict__ out) {
    __shared__ float Qs[QT * 64];
    __shared__ float Ks[KT * 64];
    __shared__ float Vs[KT * 64];
    __shared__ float Ss[QT * 65];

    const int t  = threadIdx.x;
    const int b  = blockIdx.y;
    const int q0 = blockIdx.x * QT;

    // ---- stage Q tile (swizzled) ----
    {
        const float4* src = (const float4*)(q + ((size_t)(b * N_ + q0)) * C_);
        #pragma unroll
        for (int f = t; f < QT * 16; f += 256) {
            int row = f >> 4, cc = f & 15;
            float4 val = src[f];
            *(float4*)&Qs[row * 64 + 4 * (cc ^ (row & 15))] = val;
        }
    }

    const int ti = t & 15;          // S-compute: 4x4 tile at rows 4*ti.., cols 4*tj..
    const int tj = t >> 4;
    const int r  = t >> 2;          // softmax/PV/proj: row r, channel/col quarter
    const int q4 = t & 3;
    const int c0 = q4 * 16;

    float m = -INFINITY, l = 0.f;
    float ctx[16];
    #pragma unroll
    for (int i = 0; i < 16; ++i) ctx[i] = 0.f;

    for (int k0 = 0; k0 < N_; k0 += KT) {
        // ---- stage K,V chunk (swizzled) ----
        const float4* ksrc = (const float4*)(k + ((size_t)(b * N_ + k0)) * C_);
        const float4* vsrc = (const float4*)(v + ((size_t)(b * N_ + k0)) * C_);
        __syncthreads();   // previous PV must be done before overwrite
        #pragma unroll
        for (int f = t; f < KT * 16; f += 256) {
            int row = f >> 4, cc = f & 15;
            int dst = row * 64 + 4 * (cc ^ (row & 15));
            *(float4*)&Ks[dst] = ksrc[f];
            *(float4*)&Vs[dst] = vsrc[f];
        }
        __syncthreads();

        // ---- S = (Q K^T) * 8, 4x4 register tile per thread ----
        float acc[4][4];
        #pragma unroll
        for (int a = 0; a < 4; ++a)
            #pragma unroll
            for (int bb = 0; bb < 4; ++bb) acc[a][bb] = 0.f;

        #pragma unroll
        for (int cc = 0; cc < 16; ++cc) {
            float4 qa[4], kb[4];
            #pragma unroll
            for (int a = 0; a < 4; ++a)
                qa[a] = *(const float4*)&Qs[(4 * ti + a) * 64 + 4 * (cc ^ ((4 * ti + a) & 15))];
            #pragma unroll
            for (int bb = 0; bb < 4; ++bb)
                kb[bb] = *(const float4*)&Ks[(4 * tj + bb) * 64 + 4 * (cc ^ ((4 * tj + bb) & 15))];
            #pragma unroll
            for (int a = 0; a < 4; ++a)
                #pragma unroll
                for (int bb = 0; bb < 4; ++bb) {
                    acc[a][bb] = fmaf(qa[a].x, kb[bb].x, acc[a][bb]);
                    acc[a][bb] = fmaf(qa[a].y, kb[bb].y, acc[a][bb]);
                    acc[a][bb] = fmaf(qa[a].z, kb[bb].z, acc[a][bb]);
                    acc[a][bb] = fmaf(qa[a].w, kb[bb].w, acc[a][bb]);
                }
        }
        #pragma unroll
        for (int a = 0; a < 4; ++a)
            #pragma unroll
            for (int bb = 0; bb < 4; ++bb)
                Ss[(4 * ti + a) * 65 + 4 * tj + bb] = acc[a][bb] * 8.0f;
        __syncthreads();

        // ---- online softmax: 4 lanes per row (quad shuffle reduce) ----
        float cmax = -INFINITY;
        #pragma unroll
        for (int jj = 0; jj < 16; ++jj) cmax = fmaxf(cmax, Ss[r * 65 + c0 + jj]);
        cmax = fmaxf(cmax, __shfl_xor(cmax, 1));
        cmax = fmaxf(cmax, __shfl_xor(cmax, 2));
        float mnew = fmaxf(m, cmax);
        float fac  = __expf(m - mnew);        // m=-inf first pass -> fac=0
        float ps   = 0.f;
        #pragma unroll
        for (int jj = 0; jj < 16; ++jj) {
            float p = __expf(Ss[r * 65 + c0 + jj] - mnew);
            Ss[r * 65 + c0 + jj] = p;
            ps += p;
        }
        ps += __shfl_xor(ps, 1);
        ps += __shfl_xor(ps, 2);
        l = l * fac + ps;
        m = mnew;
        __syncthreads();   // P visible to all lanes of the quad's wave

        // ---- ctx = ctx*fac + P @ V  (V reads are lane-broadcast) ----
        #pragma unroll
        for (int i = 0; i < 16; ++i) ctx[i] *= fac;
        #pragma unroll 4
        for (int j = 0; j < KT; ++j) {
            float p = Ss[r * 65 + j];
            #pragma unroll
            for (int c4 = 0; c4 < 4; ++c4) {
                float4 vv = *(const float4*)&Vs[j * 64 + 4 * ((q4 * 4 + c4) ^ (j & 15))];
                ctx[c4 * 4 + 0] = fmaf(p, vv.x, ctx[c4 * 4 + 0]);
                ctx[c4 * 4 + 1] = fmaf(p, vv.y, ctx[c4 * 4 + 1]);
                ctx[c4 * 4 + 2] = fmaf(p, vv.z, ctx[c4 * 4 + 2]);
                ctx[c4 * 4 + 3] = fmaf(p, vv.w, ctx[c4 * 4 + 3]);
            }
        }
    }

    // ---- epilogue: normalize, project through Wp (64x64), write out ----
    __syncthreads();
    float inv = 1.0f / l;
    #pragma unroll
    for (int i = 0; i < 16; ++i) Ss[r * 65 + c0 + i] = ctx[i] * inv;
    __syncthreads();

    float acc2[16];
    #pragma unroll
    for (int e = 0; e < 16; ++e) acc2[e] = bp[c0 + e];
    for (int c = 0; c < 64; ++c) {
        float cv = Ss[r * 65 + c];
        #pragma unroll
        for (int e4 = 0; e4 < 4; ++e4) {
            float4 wv4 = *(const float4*)&Wp[c * 64 + c0 + 4 * e4];
            acc2[e4 * 4 + 0] = fmaf(cv, wv4.x, acc2[e4 * 4 + 0]);
            acc2[e4 * 4 + 1] = fmaf(cv, wv4.y, acc2[e4 * 4 + 1]);
            acc2[e4 * 4 + 2] = fmaf(cv, wv4.z, acc2[e4 * 4 + 2]);
            acc2[e4 * 4 + 3] = fmaf(cv, wv4.w, acc2[e4 * 4 + 3]);
        }
    }
    float* op = out + ((size_t)(b * N_ + q0 + r)) * 64 + c0;
    #pragma unroll
    for (int e4 = 0; e4 < 4; ++e4) {
        float4 o;
        o.x = acc2[e4 * 4 + 0]; o.y = acc2[e4 * 4 + 1];
        o.z = acc2[e4 * 4 + 2]; o.w = acc2[e4 * 4 + 3];
        *(float4*)&op[4 * e4] = o;
    }
}

// ---------------------------------------------------------------------------
extern "C" void kernel_launch(void* const* d_in, const int* in_sizes, int n_in,
                              void* d_out, int out_size, void* d_ws, size_t ws_size,
                              hipStream_t stream) {
    const float* x  = (const float*)d_in[0];
    const float* wq = (const float*)d_in[1];
    const float* bq = (const float*)d_in[2];
    const float* wk = (const float*)d_in[3];
    const float* bk = (const float*)d_in[4];
    const float* wv = (const float*)d_in[5];
    const float* bv = (const float*)d_in[6];
    const float* Wp = (const float*)d_in[7];
    const float* bp = (const float*)d_in[8];
    float* out = (float*)d_out;

    const size_t elems = (size_t)B_ * N_ * C_;   // 1,605,632
    float* q = (float*)d_ws;
    float* k = q + elems;
    float* v = k + elems;

    {
        int total = (int)elems;
        int blocks = (total + 255) / 256;
        dwconv_qkv<<<blocks, 256, 0, stream>>>(x, wq, bq, wk, bk, wv, bv, q, k, v);
    }
    {
        dim3 grid(N_ / QT, B_);
        flash_attn<<<grid, 256, 0, stream>>>(q, k, v, Wp, bp, out);
    }
}

// Round 2
// 203.103 us; speedup vs baseline: 3.8226x; 3.8226x over previous
//
#include <hip/hip_runtime.h>
#include <math.h>
#include <stdint.h>

#define B_ 8
#define H_ 56
#define W_ 56
#define C_ 64
#define N_ (H_*W_)        // 3136
#define NCHUNK (N_/64)    // 49
#define QTILE 128
#define NTILE 25          // ceil(3136/128)
#define SCALE_LOG2 11.5415603271f   // 8 * log2(e): fold score-scale + exp2 conversion into q

typedef float    f32x16 __attribute__((ext_vector_type(16)));
typedef float    f32x8  __attribute__((ext_vector_type(8)));
typedef short    short8 __attribute__((ext_vector_type(8)));
typedef unsigned u32x4  __attribute__((ext_vector_type(4)));

#define GLOBAL_AS __attribute__((address_space(1)))
#define LDS_AS    __attribute__((address_space(3)))

static __device__ __forceinline__ float bf16lo_f(unsigned w) { return __uint_as_float(w << 16); }
static __device__ __forceinline__ float bf16hi_f(unsigned w) { return __uint_as_float(w & 0xFFFF0000u); }

// pack two f32 -> bf16x2 word (RNE), low = a, high = b
static __device__ __forceinline__ unsigned pack_bf2(float a, float b) {
    unsigned r;
    asm("v_cvt_pk_bf16_f32 %0, %1, %2" : "=v"(r) : "v"(a), "v"(b));
    return r;
}
static __device__ __forceinline__ float exp2_fast(float x) {
    float r;
    asm("v_exp_f32 %0, %1" : "=v"(r) : "v"(x));
    return r;
}
static __device__ __forceinline__ short8 frag_words(unsigned w0, unsigned w1, unsigned w2, unsigned w3) {
    union { u32x4 u; short8 s; } t;
    t.u = (u32x4){w0, w1, w2, w3};
    return t.s;
}
static __device__ __forceinline__ f32x16 MF(short8 a, short8 b, f32x16 c) {
    return __builtin_amdgcn_mfma_f32_32x32x16_bf16(a, b, c, 0, 0, 0);
}
// LDS fragment read: 256B rows, 16B chunks XOR-swizzled by (row&15)
static __device__ __forceinline__ short8 ldsfrag(const uint8_t* base, int row, int q16) {
    const uint4 u = *(const uint4*)(base + row * 256 + ((q16 ^ (row & 15)) * 16));
    union { uint4 a; short8 s; } t; t.a = u; return t.s;
}

// ---------------------------------------------------------------------------
// Kernel 1a: depthwise conv -> q (scaled by 8*log2e), k. Row layout per token:
// 256B = [hi bf16 c0..63][lo bf16 c0..63], 16B chunks; k rows pre-swizzled ^(n&15).
// thread = (b, n, g): channels 8g..8g+7
// ---------------------------------------------------------------------------
__global__ __launch_bounds__(256)
void dwconv_qk(const float* __restrict__ x,
               const float* __restrict__ wq, const float* __restrict__ bq,
               const float* __restrict__ wk, const float* __restrict__ bk,
               uint8_t* __restrict__ qbuf, uint8_t* __restrict__ kbuf) {
    int tid = blockIdx.x * 256 + threadIdx.x;          // 200704 total
    int g   = tid & 7;
    int n   = (tid >> 3) % N_;
    int b   = (tid >> 3) / N_;
    int w0  = n % W_, h0 = n / W_;

    f32x8 aq = *(const f32x8*)(bq + 8 * g);
    f32x8 ak = *(const f32x8*)(bk + 8 * g);
    #pragma unroll
    for (int dh = 0; dh < 3; ++dh) {
        int hh = h0 + dh - 1;
        if (hh < 0 || hh >= H_) continue;
        #pragma unroll
        for (int dw = 0; dw < 3; ++dw) {
            int ww = w0 + dw - 1;
            if (ww < 0 || ww >= W_) continue;
            f32x8 xv = *(const f32x8*)(x + (((size_t)b * H_ + hh) * W_ + ww) * C_ + 8 * g);
            int wi = (dh * 3 + dw) * C_ + 8 * g;
            aq += xv * *(const f32x8*)(wq + wi);
            ak += xv * *(const f32x8*)(wk + wi);
        }
    }
    aq *= SCALE_LOG2;

    uint4 qh4, ql4, kh4, kl4;
    unsigned* qh = (unsigned*)&qh4; unsigned* ql = (unsigned*)&ql4;
    unsigned* kh = (unsigned*)&kh4; unsigned* kl = (unsigned*)&kl4;
    #pragma unroll
    for (int j = 0; j < 4; ++j) {
        float a0 = aq[2*j], a1 = aq[2*j+1];
        qh[j] = pack_bf2(a0, a1);
        ql[j] = pack_bf2(a0 - bf16lo_f(qh[j] & 0xFFFFu), a1 - bf16hi_f(qh[j]));
        float k0 = ak[2*j], k1 = ak[2*j+1];
        kh[j] = pack_bf2(k0, k1);
        kl[j] = pack_bf2(k0 - bf16lo_f(kh[j] & 0xFFFFu), k1 - bf16hi_f(kh[j]));
    }
    size_t rb = ((size_t)(b * N_ + n)) * 256;
    *(uint4*)&qbuf[rb + g * 16]              = qh4;
    *(uint4*)&qbuf[rb + (8 + g) * 16]        = ql4;
    *(uint4*)&kbuf[rb + ((g ^ (n & 15))) * 16]       = kh4;
    *(uint4*)&kbuf[rb + (((8 + g) ^ (n & 15))) * 16] = kl4;
}

// ---------------------------------------------------------------------------
// Kernel 1b: depthwise conv -> v, stored TRANSPOSED per 64-token chunk:
// vt[b][chunk][c] row of 256B = [vh kloc0..63][vl kloc0..63], chunks ^(c&15).
// lane = channel c; thread computes 8 consecutive tokens (one w-octet).
// ---------------------------------------------------------------------------
__global__ __launch_bounds__(256)
void dwconv_vt(const float* __restrict__ x, const float* __restrict__ wv,
               const float* __restrict__ bv, uint8_t* __restrict__ vtbuf) {
    int tid = blockIdx.x * 256 + threadIdx.x;
    int c   = tid & 63;
    int oct = (tid >> 6) % 392;
    int b   = (tid >> 6) / 392;
    int n0  = oct * 8;
    int h0  = n0 / W_, w0 = n0 % W_;

    float wvv[9];
    #pragma unroll
    for (int t9 = 0; t9 < 9; ++t9) wvv[t9] = wv[t9 * C_ + c];
    float acc[8];
    float bvc = bv[c];
    #pragma unroll
    for (int i = 0; i < 8; ++i) acc[i] = bvc;

    #pragma unroll
    for (int dh = 0; dh < 3; ++dh) {
        int hh = h0 + dh - 1;
        if (hh < 0 || hh >= H_) continue;
        float xv[10];
        #pragma unroll
        for (int j = 0; j < 10; ++j) {
            int ww = w0 + j - 1;
            xv[j] = (ww >= 0 && ww < W_) ? x[(((size_t)b * H_ + hh) * W_ + ww) * C_ + c] : 0.f;
        }
        #pragma unroll
        for (int i = 0; i < 8; ++i) {
            acc[i] = fmaf(xv[i],     wvv[dh*3+0], acc[i]);
            acc[i] = fmaf(xv[i + 1], wvv[dh*3+1], acc[i]);
            acc[i] = fmaf(xv[i + 2], wvv[dh*3+2], acc[i]);
        }
    }
    uint4 vh4, vl4;
    unsigned* vh = (unsigned*)&vh4; unsigned* vl = (unsigned*)&vl4;
    #pragma unroll
    for (int j = 0; j < 4; ++j) {
        float a0 = acc[2*j], a1 = acc[2*j+1];
        vh[j] = pack_bf2(a0, a1);
        vl[j] = pack_bf2(a0 - bf16lo_f(vh[j] & 0xFFFFu), a1 - bf16hi_f(vh[j]));
    }
    int ch  = n0 >> 6;
    int ko8 = (n0 >> 3) & 7;
    size_t base = ((size_t)((b * NCHUNK + ch) * 64 + c)) * 256;
    *(uint4*)&vtbuf[base + ((ko8      ^ (c & 15))) * 16] = vh4;
    *(uint4*)&vtbuf[base + (((8+ko8)  ^ (c & 15))) * 16] = vl4;
}

// ---------------------------------------------------------------------------
// Kernel 2: MFMA flash attention. grid.x = 200 (b = bx%8 -> XCD affinity,
// tile = bx/8). 4 waves x 32 q-rows. K,Vt double-buffered LDS (64KB).
// S^T = K*Q^T via mfma(A=K, B=Q): lane owns q-row (lane&31), k = 32kt+8u+4h+r.
// ---------------------------------------------------------------------------
__global__ __launch_bounds__(256, 1)
void attn_mfma(const uint8_t* __restrict__ qbuf, const uint8_t* __restrict__ kbuf,
               const uint8_t* __restrict__ vtbuf, const float* __restrict__ Wp,
               const float* __restrict__ bp, float* __restrict__ out) {
    __shared__ __align__(16) uint8_t smem[65536];   // K:2x16KB | Vt:2x16KB

    const int t    = threadIdx.x;
    const int lane = t & 63;
    const int w    = t >> 6;
    const int h    = lane >> 5;      // half-wave
    const int l31  = lane & 31;      // q-column within wave tile
    const int b    = blockIdx.x & 7;
    const int tile = blockIdx.x >> 3;
    const int q0   = tile * QTILE;

    // ---- Q fragments (B-operand) to registers: c = 16s + 8h + j ----
    int qu = q0 + w * 32 + l31;
    int qr = qu < N_ ? qu : N_ - 1;
    const uint8_t* qrp = qbuf + ((size_t)(b * N_ + qr)) * 256;
    short8 qh[4], ql[4];
    #pragma unroll
    for (int s = 0; s < 4; ++s) {
        union { uint4 a; short8 s8; } th, tl;
        th.a = *(const uint4*)(qrp + s * 32 + h * 16);
        tl.a = *(const uint4*)(qrp + 128 + s * 32 + h * 16);
        qh[s] = th.s8; ql[s] = tl.s8;
    }

    f32x16 ctx0, ctx1;
    #pragma unroll
    for (int i = 0; i < 16; ++i) { ctx0[i] = 0.f; ctx1[i] = 0.f; }
    float mrun = -INFINITY, lrun = 0.f;

    auto stage = [&](int ch, int pb) {
        const uint8_t* ks = kbuf  + ((size_t)(b * N_ + ch * 64)) * 256;
        const uint8_t* vs = vtbuf + ((size_t)((b * NCHUNK + ch) * 64)) * 256;
        uint8_t* kd = smem + pb * 16384;
        uint8_t* vd = smem + 32768 + pb * 16384;
        #pragma unroll
        for (int i = 0; i < 4; ++i) {
            int f = (t + i * 256) * 16;
            __builtin_amdgcn_global_load_lds((const GLOBAL_AS uint32_t*)(ks + f),
                                             (LDS_AS uint32_t*)(kd + f), 16, 0, 0);
        }
        #pragma unroll
        for (int i = 0; i < 4; ++i) {
            int f = (t + i * 256) * 16;
            __builtin_amdgcn_global_load_lds((const GLOBAL_AS uint32_t*)(vs + f),
                                             (LDS_AS uint32_t*)(vd + f), 16, 0, 0);
        }
    };

    stage(0, 0);
    __syncthreads();

    for (int ch = 0; ch < NCHUNK; ++ch) {
        const int pb = ch & 1;
        const uint8_t* Kp = smem + pb * 16384;
        const uint8_t* Vp = smem + 32768 + pb * 16384;
        if (ch + 1 < NCHUNK) stage(ch + 1, pb ^ 1);

        // ---- S^T: 2 k-tiles x 4 c-steps x 3 hi/lo terms ----
        f32x16 s0, s1;
        #pragma unroll
        for (int i = 0; i < 16; ++i) { s0[i] = 0.f; s1[i] = 0.f; }
        #pragma unroll
        for (int s = 0; s < 4; ++s) {
            short8 kh0 = ldsfrag(Kp, l31,      2*s + h);
            short8 kl0 = ldsfrag(Kp, l31,      8 + 2*s + h);
            short8 kh1 = ldsfrag(Kp, 32 + l31, 2*s + h);
            short8 kl1 = ldsfrag(Kp, 32 + l31, 8 + 2*s + h);
            s0 = MF(kh0, qh[s], s0);
            s1 = MF(kh1, qh[s], s1);
            s0 = MF(kh0, ql[s], s0);
            s1 = MF(kh1, ql[s], s1);
            s0 = MF(kl0, qh[s], s0);
            s1 = MF(kl1, qh[s], s1);
        }

        // ---- online softmax (log2 domain), lane-local + partner shuffle ----
        float mloc = s0[0];
        #pragma unroll
        for (int i = 1; i < 16; ++i) mloc = fmaxf(mloc, s0[i]);
        #pragma unroll
        for (int i = 0; i < 16; ++i) mloc = fmaxf(mloc, s1[i]);
        float mw = fmaxf(mloc, __shfl_xor(mloc, 32));
        if (mw > mrun + 8.f) {              // defer-max (T13), log2 units
            float fac = exp2_fast(mrun - mw);
            lrun *= fac;
            #pragma unroll
            for (int i = 0; i < 16; ++i) { ctx0[i] *= fac; ctx1[i] *= fac; }
            mrun = mw;
        }
        float p0[16], p1[16];
        float ls = 0.f;
        #pragma unroll
        for (int i = 0; i < 16; ++i) {
            p0[i] = exp2_fast(s0[i] - mrun); ls += p0[i];
            p1[i] = exp2_fast(s1[i] - mrun); ls += p1[i];
        }
        lrun += ls + __shfl_xor(ls, 32);

        // ---- P -> bf16 hi/lo packed words (word j = regs 2j,2j+1) ----
        unsigned hw0[8], lw0[8], hw1[8], lw1[8];
        #pragma unroll
        for (int j = 0; j < 8; ++j) {
            hw0[j] = pack_bf2(p0[2*j], p0[2*j+1]);
            lw0[j] = pack_bf2(p0[2*j]   - bf16lo_f(hw0[j] & 0xFFFFu),
                              p0[2*j+1] - bf16hi_f(hw0[j]));
            hw1[j] = pack_bf2(p1[2*j], p1[2*j+1]);
            lw1[j] = pack_bf2(p1[2*j]   - bf16lo_f(hw1[j] & 0xFFFFu),
                              p1[2*j+1] - bf16hi_f(hw1[j]));
        }

        // ---- PV: partner word exchange -> B-frags; A = Vt hi from LDS ----
#define PV_STEP(S, HW, LW) {                                                  \
        const int base = 4 * ((S) & 1);                                       \
        unsigned a0 = HW[base], a1 = HW[base+1], a2 = HW[base+2], a3 = HW[base+3]; \
        unsigned c0 = LW[base], c1 = LW[base+1], c2 = LW[base+2], c3 = LW[base+3]; \
        unsigned sh0 = __shfl_xor(h ? a0 : a2, 32);                           \
        unsigned sh1 = __shfl_xor(h ? a1 : a3, 32);                           \
        unsigned sl0 = __shfl_xor(h ? c0 : c2, 32);                           \
        unsigned sl1 = __shfl_xor(h ? c1 : c3, 32);                           \
        short8 bh = frag_words(h ? sh0 : a0, h ? sh1 : a1,                    \
                               h ? a2 : sh0, h ? a3 : sh1);                   \
        short8 bl = frag_words(h ? sl0 : c0, h ? sl1 : c1,                    \
                               h ? c2 : sl0, h ? c3 : sl1);                   \
        short8 v0f = ldsfrag(Vp, l31,      2*(S) + h);                        \
        short8 v1f = ldsfrag(Vp, 32 + l31, 2*(S) + h);                        \
        ctx0 = MF(v0f, bh, ctx0);  ctx1 = MF(v1f, bh, ctx1);                  \
        ctx0 = MF(v0f, bl, ctx0);  ctx1 = MF(v1f, bl, ctx1);                  \
    }
        PV_STEP(0, hw0, lw0)
        PV_STEP(1, hw0, lw0)
        PV_STEP(2, hw1, lw1)
        PV_STEP(3, hw1, lw1)
#undef PV_STEP

        __syncthreads();
    }

    // ---- epilogue: normalize, project (fp32 VALU), pair-sum, store ----
    float inv = 1.f / lrun;
    float4 yv4[16];
    #pragma unroll
    for (int e4 = 0; e4 < 16; ++e4) yv4[e4] = make_float4(0.f, 0.f, 0.f, 0.f);

    #pragma unroll
    for (int u = 0; u < 4; ++u)
        #pragma unroll
        for (int rr = 0; rr < 4; ++rr) {
            float cv0 = ctx0[4*u + rr] * inv;
            float cv1 = ctx1[4*u + rr] * inv;
            int c = 8*u + 4*h + rr;
            const float4* wr0 = (const float4*)&Wp[c * 64];
            const float4* wr1 = (const float4*)&Wp[(c + 32) * 64];
            #pragma unroll
            for (int e4 = 0; e4 < 16; ++e4) {
                float4 w0v = wr0[e4], w1v = wr1[e4];
                yv4[e4].x = fmaf(cv0, w0v.x, fmaf(cv1, w1v.x, yv4[e4].x));
                yv4[e4].y = fmaf(cv0, w0v.y, fmaf(cv1, w1v.y, yv4[e4].y));
                yv4[e4].z = fmaf(cv0, w0v.z, fmaf(cv1, w1v.z, yv4[e4].z));
                yv4[e4].w = fmaf(cv0, w0v.w, fmaf(cv1, w1v.w, yv4[e4].w));
            }
        }
    // sum the two half-wave partials (lanes l and l^32 hold complementary c-halves)
    #pragma unroll
    for (int e4 = 0; e4 < 16; ++e4) {
        yv4[e4].x += __shfl_xor(yv4[e4].x, 32);
        yv4[e4].y += __shfl_xor(yv4[e4].y, 32);
        yv4[e4].z += __shfl_xor(yv4[e4].z, 32);
        yv4[e4].w += __shfl_xor(yv4[e4].w, 32);
    }
    if (h == 0 && qu < N_) {
        float* orow = out + ((size_t)(b * N_ + qu)) * 64;
        #pragma unroll
        for (int e4 = 0; e4 < 16; ++e4) {
            const float4 bpv = *(const float4*)&bp[e4 * 4];
            float4 o;
            o.x = yv4[e4].x + bpv.x; o.y = yv4[e4].y + bpv.y;
            o.z = yv4[e4].z + bpv.z; o.w = yv4[e4].w + bpv.w;
            *(float4*)&orow[e4 * 4] = o;
        }
    }
}

// ---------------------------------------------------------------------------
extern "C" void kernel_launch(void* const* d_in, const int* in_sizes, int n_in,
                              void* d_out, int out_size, void* d_ws, size_t ws_size,
                              hipStream_t stream) {
    const float* x  = (const float*)d_in[0];
    const float* wq = (const float*)d_in[1];
    const float* bq = (const float*)d_in[2];
    const float* wk = (const float*)d_in[3];
    const float* bk = (const float*)d_in[4];
    const float* wv = (const float*)d_in[5];
    const float* bv = (const float*)d_in[6];
    const float* Wp = (const float*)d_in[7];
    const float* bp = (const float*)d_in[8];
    float* out = (float*)d_out;

    const size_t bytes_per = (size_t)B_ * N_ * 256;   // 6,422,528
    uint8_t* qbuf  = (uint8_t*)d_ws;
    uint8_t* kbuf  = qbuf + bytes_per;
    uint8_t* vtbuf = kbuf + bytes_per;

    dwconv_qk<<<784, 256, 0, stream>>>(x, wq, bq, wk, bk, qbuf, kbuf);
    dwconv_vt<<<784, 256, 0, stream>>>(x, wv, bv, vtbuf);
    attn_mfma<<<200, 256, 0, stream>>>(qbuf, kbuf, vtbuf, Wp, bp, out);
}

// Round 3
// 188.595 us; speedup vs baseline: 4.1167x; 1.0769x over previous
//
#include <hip/hip_runtime.h>
#include <math.h>
#include <stdint.h>

#define B_ 8
#define H_ 56
#define W_ 56
#define C_ 64
#define N_ (H_*W_)        // 3136
#define KT 32
#define NCH (N_/KT)       // 98
#define QTILE 128
#define NTILES 25         // ceil(3136/128)
#define KSPLIT 4
#define SCALE_LOG2 11.5415603271f   // 8 * log2(e)

typedef float    f32x16 __attribute__((ext_vector_type(16)));
typedef short    short8 __attribute__((ext_vector_type(8)));
typedef unsigned u32x4  __attribute__((ext_vector_type(4)));

#define GLOBAL_AS __attribute__((address_space(1)))
#define LDS_AS    __attribute__((address_space(3)))

static __device__ __forceinline__ float bf16lo_f(unsigned w) { return __uint_as_float(w << 16); }
static __device__ __forceinline__ float bf16hi_f(unsigned w) { return __uint_as_float(w & 0xFFFF0000u); }
static __device__ __forceinline__ unsigned pack_bf2(float a, float b) {
    unsigned r;
    asm("v_cvt_pk_bf16_f32 %0, %1, %2" : "=v"(r) : "v"(a), "v"(b));
    return r;
}
static __device__ __forceinline__ float exp2_fast(float x) {
    float r;
    asm("v_exp_f32 %0, %1" : "=v"(r) : "v"(x));
    return r;
}
static __device__ __forceinline__ short8 frag_words(unsigned w0, unsigned w1, unsigned w2, unsigned w3) {
    union { u32x4 u; short8 s; } t;
    t.u = (u32x4){w0, w1, w2, w3};
    return t.s;
}
static __device__ __forceinline__ f32x16 MF(short8 a, short8 b, f32x16 c) {
    return __builtin_amdgcn_mfma_f32_32x32x16_bf16(a, b, c, 0, 0, 0);
}
// K LDS fragment: 256B rows, 16B chunks XOR-swizzled by (row&15)
static __device__ __forceinline__ short8 ldsfragK(const uint8_t* base, int row, int q16) {
    const uint4 u = *(const uint4*)(base + row * 256 + ((q16 ^ (row & 15)) * 16));
    union { uint4 a; short8 s; } t; t.a = u; return t.s;
}
// V LDS fragment: 80B-padded rows (bank spread), plain word index
static __device__ __forceinline__ short8 ldsfragV(const uint8_t* base, int row, int wd) {
    const uint4 u = *(const uint4*)(base + row * 80 + wd * 16);
    union { uint4 a; short8 s; } t; t.a = u; return t.s;
}

// ---------------------------------------------------------------------------
// Kernel 1 (fused): dwconv -> q,k (token-major hi/lo rows) + v (transposed hi).
// Block = 256 threads = 32 consecutive tokens x 64 ch. thread: c=t&63, oct=t>>6.
// Sliding-window per octet (8 tokens along w; 56 = 7 octets, never crosses row).
// q,k transposed to token-major via LDS.
// ---------------------------------------------------------------------------
__global__ __launch_bounds__(256)
void dwconv_fused(const float* __restrict__ x,
                  const float* __restrict__ wq, const float* __restrict__ bq,
                  const float* __restrict__ wk, const float* __restrict__ bk,
                  const float* __restrict__ wv, const float* __restrict__ bv,
                  uint8_t* __restrict__ qbuf, uint8_t* __restrict__ kbuf,
                  uint8_t* __restrict__ vtbuf) {
    __shared__ float tq[32][68];
    __shared__ float tk[32][68];

    const int t   = threadIdx.x;
    const int c   = t & 63;
    const int oct = t >> 6;
    const int og  = blockIdx.x * 4 + oct;     // global octet
    const int b   = og / (N_ / 8);
    const int po  = og % (N_ / 8);            // octet within batch
    const int h0  = po / 7;
    const int w0  = (po - h0 * 7) * 8;
    const int n0  = po * 8;

    float q8[8], k8[8], v8[8];
    const float bqc = bq[c], bkc = bk[c], bvc = bv[c];
    #pragma unroll
    for (int i = 0; i < 8; ++i) { q8[i] = bqc; k8[i] = bkc; v8[i] = bvc; }

    #pragma unroll
    for (int dh = 0; dh < 3; ++dh) {
        int hh = h0 + dh - 1;
        if (hh < 0 || hh >= H_) continue;
        float xv[10];
        #pragma unroll
        for (int j = 0; j < 10; ++j) {
            int ww = w0 + j - 1;
            xv[j] = (ww >= 0 && ww < W_) ? x[(((size_t)b * H_ + hh) * W_ + ww) * C_ + c] : 0.f;
        }
        #pragma unroll
        for (int dw = 0; dw < 3; ++dw) {
            float fq = wq[(dh * 3 + dw) * C_ + c];
            float fk = wk[(dh * 3 + dw) * C_ + c];
            float fv = wv[(dh * 3 + dw) * C_ + c];
            #pragma unroll
            for (int i = 0; i < 8; ++i) {
                float xs = xv[i + dw];
                q8[i] = fmaf(xs, fq, q8[i]);
                k8[i] = fmaf(xs, fk, k8[i]);
                v8[i] = fmaf(xs, fv, v8[i]);
            }
        }
    }
    #pragma unroll
    for (int i = 0; i < 8; ++i) q8[i] *= SCALE_LOG2;

    // ---- v: pack hi, store transposed: vt[b][chunk32][c][word=oct-in-chunk]
    {
        uint4 vh4; unsigned* vh = (unsigned*)&vh4;
        #pragma unroll
        for (int j = 0; j < 4; ++j) vh[j] = pack_bf2(v8[2*j], v8[2*j+1]);
        int ch32 = po >> 2, ko = po & 3;
        *(uint4*)&vtbuf[((size_t)(b * NCH + ch32) * 64 + c) * 64 + ko * 16] = vh4;
    }

    // ---- q,k: LDS transpose to token-major, pack hi/lo, store ----
    #pragma unroll
    for (int i = 0; i < 8; ++i) { tq[oct * 8 + i][c] = q8[i]; tk[oct * 8 + i][c] = k8[i]; }
    __syncthreads();

    const int g2 = t & 7;       // channel group (8 ch)
    const int tl = t >> 3;      // token-local 0..31
    float qv[8], kv[8];
    *(float4*)&qv[0] = *(const float4*)&tq[tl][8 * g2];
    *(float4*)&qv[4] = *(const float4*)&tq[tl][8 * g2 + 4];
    *(float4*)&kv[0] = *(const float4*)&tk[tl][8 * g2];
    *(float4*)&kv[4] = *(const float4*)&tk[tl][8 * g2 + 4];

    uint4 qh4, ql4, kh4, kl4;
    unsigned* qh = (unsigned*)&qh4; unsigned* ql = (unsigned*)&ql4;
    unsigned* kh = (unsigned*)&kh4; unsigned* kl = (unsigned*)&kl4;
    #pragma unroll
    for (int j = 0; j < 4; ++j) {
        float a0 = qv[2*j], a1 = qv[2*j+1];
        qh[j] = pack_bf2(a0, a1);
        ql[j] = pack_bf2(a0 - bf16lo_f(qh[j] & 0xFFFFu), a1 - bf16hi_f(qh[j]));
        float k0 = kv[2*j], k1 = kv[2*j+1];
        kh[j] = pack_bf2(k0, k1);
        kl[j] = pack_bf2(k0 - bf16lo_f(kh[j] & 0xFFFFu), k1 - bf16hi_f(kh[j]));
    }
    const int nf = blockIdx.x * 32 + tl;      // flat token (b*N_+n); batch mult of 32
    size_t rb = (size_t)nf * 256;
    *(uint4*)&qbuf[rb + g2 * 16]                    = qh4;
    *(uint4*)&qbuf[rb + (8 + g2) * 16]              = ql4;
    *(uint4*)&kbuf[rb + ((g2 ^ (nf & 15))) * 16]       = kh4;
    *(uint4*)&kbuf[rb + (((8 + g2) ^ (nf & 15))) * 16] = kl4;
}

// ---------------------------------------------------------------------------
// Kernel 2: MFMA flash attention, K-split partials.
// grid = 800: bx = ((ks*25+tile)<<3)|b. 4 waves x 32 q-rows. KT=32 chunks.
// LDS: K 2x8KB (swizzled) + V 2x5KB (80B-pad rows) = 26KB.
// ---------------------------------------------------------------------------
__global__ __launch_bounds__(256, 3)
void attn_part(const uint8_t* __restrict__ qbuf, const uint8_t* __restrict__ kbuf,
               const uint8_t* __restrict__ vtbuf,
               float* __restrict__ part, float* __restrict__ ml) {
    __shared__ __align__(16) uint8_t smem[16384 + 10240];

    const int t    = threadIdx.x;
    const int lane = t & 63;
    const int wv_  = t >> 6;         // wave id
    const int h    = lane >> 5;
    const int l31  = lane & 31;
    const int bx   = blockIdx.x;
    const int b    = bx & 7;
    const int r2   = bx >> 3;        // 0..99
    const int ks   = r2 / NTILES;
    const int tile = r2 % NTILES;
    const int q0   = tile * QTILE;

    const int c_beg = (NCH * ks) / KSPLIT;
    const int c_end = (NCH * (ks + 1)) / KSPLIT;

    // ---- Q fragments: channels c = 16s + 8h + j ----
    const int qu = q0 + wv_ * 32 + l31;
    const int qr = qu < N_ ? qu : N_ - 1;
    const uint8_t* qrp = qbuf + ((size_t)(b * N_ + qr)) * 256;
    short8 qh[4], ql[4];
    #pragma unroll
    for (int s = 0; s < 4; ++s) {
        union { uint4 a; short8 s8; } th, tl_;
        th.a  = *(const uint4*)(qrp + s * 32 + h * 16);
        tl_.a = *(const uint4*)(qrp + 128 + s * 32 + h * 16);
        qh[s] = th.s8; ql[s] = tl_.s8;
    }

    f32x16 ctx0, ctx1;
    #pragma unroll
    for (int i = 0; i < 16; ++i) { ctx0[i] = 0.f; ctx1[i] = 0.f; }
    float mrun = -INFINITY, lrun = 0.f;

    // V stage slot mapping (fixed per thread): slot -> (c = slot/5, j = slot%5)
    const int slA = t, slB = 256 + t;
    const int vsA = (slA / 5) * 64 + ((slA % 5) == 4 ? 0 : (slA % 5)) * 16;
    const int vsB = (slB / 5) * 64 + ((slB % 5) == 4 ? 0 : (slB % 5)) * 16;

    auto stage = [&](int ch, int pb) {
        const uint8_t* ksrc = kbuf  + ((size_t)(b * N_ + ch * KT)) * 256;
        const uint8_t* vsrc = vtbuf + ((size_t)(b * NCH + ch)) * 4096;
        uint8_t* kd = smem + pb * 8192;
        uint8_t* vd = smem + 16384 + pb * 5120;
        __builtin_amdgcn_global_load_lds((const GLOBAL_AS uint32_t*)(ksrc + t * 16),
                                         (LDS_AS uint32_t*)(kd + t * 16), 16, 0, 0);
        __builtin_amdgcn_global_load_lds((const GLOBAL_AS uint32_t*)(ksrc + t * 16 + 4096),
                                         (LDS_AS uint32_t*)(kd + t * 16 + 4096), 16, 0, 0);
        __builtin_amdgcn_global_load_lds((const GLOBAL_AS uint32_t*)(vsrc + vsA),
                                         (LDS_AS uint32_t*)(vd + slA * 16), 16, 0, 0);
        if (t < 64)
            __builtin_amdgcn_global_load_lds((const GLOBAL_AS uint32_t*)(vsrc + vsB),
                                             (LDS_AS uint32_t*)(vd + slB * 16), 16, 0, 0);
    };

    stage(c_beg, 0);
    __syncthreads();

    for (int ch = c_beg; ch < c_end; ++ch) {
        const int pb = (ch - c_beg) & 1;
        const uint8_t* Kp = smem + pb * 8192;
        const uint8_t* Vp = smem + 16384 + pb * 5120;
        if (ch + 1 < c_end) stage(ch + 1, pb ^ 1);

        // ---- S^T = K * Q^T (hi/lo 3-term), one 32-row k-tile ----
        f32x16 s0;
        #pragma unroll
        for (int i = 0; i < 16; ++i) s0[i] = 0.f;
        #pragma unroll
        for (int s = 0; s < 4; ++s) {
            short8 kh0 = ldsfragK(Kp, l31, 2 * s + h);
            short8 kl0 = ldsfragK(Kp, l31, 8 + 2 * s + h);
            s0 = MF(kh0, qh[s], s0);
            s0 = MF(kh0, ql[s], s0);
            s0 = MF(kl0, qh[s], s0);
        }

        // ---- online softmax (log2 domain) ----
        float mloc = s0[0];
        #pragma unroll
        for (int i = 1; i < 16; ++i) mloc = fmaxf(mloc, s0[i]);
        float mw = fmaxf(mloc, __shfl_xor(mloc, 32));
        if (mw > mrun + 8.f) {
            float fac = exp2_fast(mrun - mw);
            lrun *= fac;
            #pragma unroll
            for (int i = 0; i < 16; ++i) { ctx0[i] *= fac; ctx1[i] *= fac; }
            mrun = mw;
        }
        float p0[16];
        float lsum = 0.f;
        #pragma unroll
        for (int i = 0; i < 16; ++i) { p0[i] = exp2_fast(s0[i] - mrun); lsum += p0[i]; }
        lrun += lsum + __shfl_xor(lsum, 32);

        // ---- P -> bf16 hi/lo words ----
        unsigned hw0[8], lw0[8];
        #pragma unroll
        for (int j = 0; j < 8; ++j) {
            hw0[j] = pack_bf2(p0[2*j], p0[2*j+1]);
            lw0[j] = pack_bf2(p0[2*j]   - bf16lo_f(hw0[j] & 0xFFFFu),
                              p0[2*j+1] - bf16hi_f(hw0[j]));
        }

        // ---- PV ----
#define PV_STEP(S) {                                                          \
        const int base = 4 * (S);                                             \
        unsigned a0 = hw0[base], a1 = hw0[base+1], a2 = hw0[base+2], a3 = hw0[base+3]; \
        unsigned c0 = lw0[base], c1 = lw0[base+1], c2 = lw0[base+2], c3 = lw0[base+3]; \
        unsigned sh0 = __shfl_xor(h ? a0 : a2, 32);                           \
        unsigned sh1 = __shfl_xor(h ? a1 : a3, 32);                           \
        unsigned sl0 = __shfl_xor(h ? c0 : c2, 32);                           \
        unsigned sl1 = __shfl_xor(h ? c1 : c3, 32);                           \
        short8 bh = frag_words(h ? sh0 : a0, h ? sh1 : a1,                    \
                               h ? a2 : sh0, h ? a3 : sh1);                   \
        short8 bl = frag_words(h ? sl0 : c0, h ? sl1 : c1,                    \
                               h ? c2 : sl0, h ? c3 : sl1);                   \
        short8 v0f = ldsfragV(Vp, l31,      2 * (S) + h);                     \
        short8 v1f = ldsfragV(Vp, 32 + l31, 2 * (S) + h);                     \
        ctx0 = MF(v0f, bh, ctx0);  ctx1 = MF(v1f, bh, ctx1);                  \
        ctx0 = MF(v0f, bl, ctx0);  ctx1 = MF(v1f, bl, ctx1);                  \
    }
        PV_STEP(0)
        PV_STEP(1)
#undef PV_STEP

        __syncthreads();
    }

    // ---- write partials: part[bx][c][128], ml[bx][q][2] ----
    float* pbase = part + (size_t)bx * 8192 + (wv_ * 32 + l31);
    #pragma unroll
    for (int u = 0; u < 4; ++u)
        #pragma unroll
        for (int rr = 0; rr < 4; ++rr) {
            int cc = 8 * u + 4 * h + rr;
            pbase[(size_t)cc * 128]        = ctx0[4*u + rr];
            pbase[(size_t)(cc + 32) * 128] = ctx1[4*u + rr];
        }
    if (h == 0)
        ((float2*)ml)[(size_t)bx * 128 + wv_ * 32 + l31] = make_float2(mrun, lrun);
}

// ---------------------------------------------------------------------------
// Kernel 3: combine 4 K-split partials + projection. grid = 200 (b,tile).
// ---------------------------------------------------------------------------
__global__ __launch_bounds__(256)
void combine(const float* __restrict__ part, const float* __restrict__ ml,
             const float* __restrict__ Wp, const float* __restrict__ bp,
             float* __restrict__ out) {
    __shared__ float cm[64][132];      // normalized merged ctx, c-major
    __shared__ float fac[KSPLIT][128];

    const int bt = blockIdx.x;
    const int b = bt & 7, tile = bt >> 3;
    const int t = threadIdx.x;

    if (t < 128) {
        float m[KSPLIT], l[KSPLIT];
        #pragma unroll
        for (int ks = 0; ks < KSPLIT; ++ks) {
            float2 v = ((const float2*)ml)[((size_t)((ks * NTILES + tile) * 8 + b)) * 128 + t];
            m[ks] = v.x; l[ks] = v.y;
        }
        float M = fmaxf(fmaxf(m[0], m[1]), fmaxf(m[2], m[3]));
        float L = 0.f;
        float f[KSPLIT];
        #pragma unroll
        for (int ks = 0; ks < KSPLIT; ++ks) { f[ks] = exp2f(m[ks] - M); L += l[ks] * f[ks]; }
        float inv = 1.f / L;
        #pragma unroll
        for (int ks = 0; ks < KSPLIT; ++ks) fac[ks][t] = f[ks] * inv;
    }
    __syncthreads();

    // merge: thread -> (c = t>>2, qg = t&3), 32 q's each
    {
        const int c = t >> 2, qg = t & 3;
        #pragma unroll
        for (int j = 0; j < 8; ++j) {
            int q = qg * 32 + j * 4;
            float4 acc = make_float4(0.f, 0.f, 0.f, 0.f);
            #pragma unroll
            for (int ks = 0; ks < KSPLIT; ++ks) {
                const float4 p4 = *(const float4*)&part[(((size_t)((ks * NTILES + tile) * 8 + b)) * 64 + c) * 128 + q];
                const float4 f4 = *(const float4*)&fac[ks][q];
                acc.x = fmaf(p4.x, f4.x, acc.x);
                acc.y = fmaf(p4.y, f4.y, acc.y);
                acc.z = fmaf(p4.z, f4.z, acc.z);
                acc.w = fmaf(p4.w, f4.w, acc.w);
            }
            *(float4*)&cm[c][q] = acc;
        }
    }
    __syncthreads();

    // projection: thread -> (q = t>>1, eh = t&1), 32 e-cols
    {
        const int q = t >> 1, eh = t & 1;
        float4 y[8];
        #pragma unroll
        for (int e = 0; e < 8; ++e) y[e] = *(const float4*)&bp[eh * 32 + e * 4];
        for (int cc = 0; cc < 64; ++cc) {
            float v = cm[cc][q];
            const float4* w4 = (const float4*)&Wp[cc * 64 + eh * 32];
            #pragma unroll
            for (int e = 0; e < 8; ++e) {
                float4 wv4 = w4[e];
                y[e].x = fmaf(v, wv4.x, y[e].x);
                y[e].y = fmaf(v, wv4.y, y[e].y);
                y[e].z = fmaf(v, wv4.z, y[e].z);
                y[e].w = fmaf(v, wv4.w, y[e].w);
            }
        }
        const int n = tile * QTILE + q;
        if (n < N_) {
            float4* op = (float4*)&out[((size_t)b * N_ + n) * 64 + eh * 32];
            #pragma unroll
            for (int e = 0; e < 8; ++e) op[e] = y[e];
        }
    }
}

// ---------------------------------------------------------------------------
extern "C" void kernel_launch(void* const* d_in, const int* in_sizes, int n_in,
                              void* d_out, int out_size, void* d_ws, size_t ws_size,
                              hipStream_t stream) {
    const float* x  = (const float*)d_in[0];
    const float* wq = (const float*)d_in[1];
    const float* bq = (const float*)d_in[2];
    const float* wk = (const float*)d_in[3];
    const float* bk = (const float*)d_in[4];
    const float* wv = (const float*)d_in[5];
    const float* bv = (const float*)d_in[6];
    const float* Wp = (const float*)d_in[7];
    const float* bp = (const float*)d_in[8];
    float* out = (float*)d_out;

    const size_t qk_bytes = (size_t)B_ * N_ * 256;          // 6,422,528 each
    const size_t vt_bytes = (size_t)B_ * NCH * 64 * 64;     // 3,211,264
    uint8_t* qbuf  = (uint8_t*)d_ws;
    uint8_t* kbuf  = qbuf + qk_bytes;
    uint8_t* vtbuf = kbuf + qk_bytes;
    float*   partp = (float*)(vtbuf + vt_bytes);            // [800][64][128]
    float*   mlp   = partp + (size_t)800 * 64 * 128;        // [800][128][2]

    dwconv_fused<<<784, 256, 0, stream>>>(x, wq, bq, wk, bk, wv, bv, qbuf, kbuf, vtbuf);
    attn_part<<<8 * NTILES * KSPLIT, 256, 0, stream>>>(qbuf, kbuf, vtbuf, partp, mlp);
    combine<<<8 * NTILES, 256, 0, stream>>>(partp, mlp, Wp, bp, out);
}